// Round 10
// baseline (184.769 us; speedup 1.0000x reference)
//
#include <hip/hip_runtime.h>
#include <hip/hip_bf16.h>

// out[b,o,hw] = sum_c W[o,c] * relu(x[b,c,hw]*scale[c] + shift[c])
// B=256, Cin=2112, Cout=192, HW=49, fp32 in HBM, bf16 MFMA internally.
//
// R17: T3/T4 — global_load_lds staging + counted vmcnt, never drain.
// All prior structures (66/11 barriers, wave regrouping, write-/read-side
// transpose, K-split TLP) sat at fused ~50us, all pipes <20% busy: the
// invariant was the per-step pipeline DRAIN (lgkmcnt(0) + compiler vmem
// waits around reg-staged rings) = m233's 2-phase stall. Fix (m218's
// measured +38-73% lever): stage x via global_load_lds into a 4-deep
// LINEAR fp32 LDS ring (slab padded to 8KB; each of 8 waves DMAs 1KB =
// one inst/step), transpose+BN on the READ side (R14-proven addressing),
// ZERO ds_writes -> zero lgkm drains, and one manual s_waitcnt vmcnt(11)
// per step (static count: 3 stage ops + 8 A-loads in flight) so 24KB of
// x-loads stay in flight ACROSS barriers. Stage issued after the barrier
// -> ring slot g-1 reuse provably race-free. Tail steps use vmcnt(0).
// K-split x2 (2 blocks/CU) + par/add epilogue verbatim from R16 (passed).

#define CIN    2112
#define COUT   192
#define HWS    49
#define BK     32
#define NK32   (CIN / BK)          // 66 granules total
#define HALF   (NK32 / 2)          // 33 granules per K-half
#define CHALF  (HALF * BK)         // 1056 channels per half
#define EPSV   1e-5f
#define SLABF  (BK * HWS)          // 1568 floats per granule slab
#define PADF   2048                // padded slab floats (8KB, 8 waves x 1KB)
#define OUTEL  (COUT * HWS)        // 9408 floats per image

typedef __bf16 bf16;
typedef __attribute__((ext_vector_type(8))) __bf16 bf16x8;
typedef __attribute__((ext_vector_type(4))) float  f32x4;

#define GLD_LDS16(src, dst) __builtin_amdgcn_global_load_lds(                 \
    (const __attribute__((address_space(1))) void*)(src),                     \
    (__attribute__((address_space(3))) void*)(dst), 16, 0, 0)

// ---------- kernel 1: W fp32 -> bf16 in A-fragment order (unchanged) ----------
__global__ __launch_bounds__(256)
void w_repack_kernel(const float* __restrict__ W, bf16* __restrict__ Wb) {
    const int t = blockIdx.x * 256 + threadIdx.x;       // 66*12*64 = 50688
    if (t >= NK32 * 12 * 64) return;
    const int lane = t & 63;
    const int gmt  = (t >> 6) % 12;
    const int ks   = t / (12 * 64);
    const int row  = gmt * 16 + (lane & 15);
    const int k    = ks * BK + (lane >> 4) * 8;
    const float* src = W + (size_t)row * CIN + k;
    f32x4 a = *(const f32x4*)src;
    f32x4 c = *(const f32x4*)(src + 4);
    bf16x8 o;
    #pragma unroll
    for (int j = 0; j < 4; j++) { o[j] = (bf16)a[j]; o[j + 4] = (bf16)c[j]; }
    *(bf16x8*)(Wb + (size_t)t * 8) = o;
}

// ---------- kernel 2: fused BN+ReLU+GEMM, gload_lds ring, counted vmcnt ----------
__global__ __launch_bounds__(512, 4)
void fused_kernel(const float* __restrict__ x,
                  const float* __restrict__ gamma,
                  const float* __restrict__ beta,
                  const float* __restrict__ rmean,
                  const float* __restrict__ rvar,
                  const bf16* __restrict__ Wb,
                  float* __restrict__ par)
{
    __shared__ __align__(16) float2 ss[CHALF];       // half's BN params
    __shared__ __align__(16) float  xr[4][PADF];     // 4-deep fp32 slab ring

    const int tid = threadIdx.x;
    const int b   = blockIdx.x >> 1;                 // image
    const int kh  = blockIdx.x & 1;                  // K-half
    const int g0  = kh * HALF;                       // first global granule
    const int c0  = kh * CHALF;                      // first channel

    // BN params for this half -> LDS
    for (int c = tid; c < CHALF; c += 512) {
        const int gc = c0 + c;
        float inv = rsqrtf(rvar[gc] + EPSV);
        float s   = gamma[gc] * inv;
        ss[c] = make_float2(s, beta[gc] - rmean[gc] * s);
    }

    const int lane = tid & 63;
    const int wv   = tid >> 6;        // 0..7
    const int mg   = wv & 3;          // 48 Cout rows
    const int ng   = wv >> 2;         // 32 hw cols
    const int l15  = lane & 15;
    const int q    = lane >> 4;

    // ---- staging: wave wv DMAs floats [wv*256, wv*256+256) of each slab.
    const float* xhalf = x + (size_t)b * (CIN * HWS) + (size_t)c0 * HWS;
    const int fi    = wv * 256 + lane * 4;           // float index in padded slab
    const bool fok  = fi < SLABF;                    // pad lanes read clamped src
    const int  fsrc = fok ? fi : 1552;               // safe aligned in-slab addr

    // ---- read-side B-frag addressing (R14-proven)
    const int hwc0 = ng * 32 + l15;                  // <= 47, always valid
    int hwc1 = ng * 32 + 16 + l15;
    if (hwc1 > 48) hwc1 = 48;                        // dup col 48 (discarded)
    const int rb0 = q * 8 * HWS + hwc0;
    const int rb1 = q * 8 * HWS + hwc1;

    const bf16* apL = Wb + (size_t)(mg * 3) * 512 + (size_t)lane * 8;

    f32x4 acc[3][2];
    #pragma unroll
    for (int mt = 0; mt < 3; mt++) { acc[mt][0] = (f32x4)(0.f); acc[mt][1] = (f32x4)(0.f); }

    // A-frag parity ring, preloaded granules g0, g0+1
    bf16x8 arE[3], arO[3];
    #pragma unroll
    for (int mt = 0; mt < 3; mt++) {
        arE[mt] = *(const bf16x8*)(apL + (size_t)g0 * 6144 + (size_t)(mt * 512));
        arO[mt] = *(const bf16x8*)(apL + (size_t)(g0 + 1) * 6144 + (size_t)(mt * 512));
    }

    // prologue: DMA tiles 0,1,2 into slots 0,1,2; drain once; sync.
    GLD_LDS16(xhalf + (size_t)0 * SLABF + fsrc, &xr[0][fi]);
    GLD_LDS16(xhalf + (size_t)1 * SLABF + fsrc, &xr[1][fi]);
    GLD_LDS16(xhalf + (size_t)2 * SLABF + fsrc, &xr[2][fi]);
    asm volatile("s_waitcnt vmcnt(0)" ::: "memory");
    __syncthreads();   // ss + tiles 0-2 ready

    // one step (local granule gl):
    //  [wait vmcnt][barrier][stage gl+3][read tile gl + BN + 6 MFMA][A gl+2]
    // Static count: newer-than-stage(gl) at the wait = 3 A-loads (step gl-3)
    // + (stage+3A) x2 (steps gl-2, gl-1) = 11. Stage AFTER the barrier makes
    // slot (gl+3)&3 == (gl-1)&3 reuse race-free (all waves finished gl-1).
    auto STEP = [&](int gl, bf16x8 (&ar)[3], bool counted) {
        if (counted) asm volatile("s_waitcnt vmcnt(11)" ::: "memory");
        else         asm volatile("s_waitcnt vmcnt(0)"  ::: "memory");
        __builtin_amdgcn_sched_barrier(0);
        __builtin_amdgcn_s_barrier();
        __builtin_amdgcn_sched_barrier(0);

        if (gl + 3 <= HALF - 1)                       // uniform for gl<=29
            GLD_LDS16(xhalf + (size_t)(gl + 3) * SLABF + fsrc,
                      &xr[(gl + 3) & 3][fi]);
        __builtin_amdgcn_sched_barrier(0);

        const float* bp = &xr[gl & 3][0];
        float xf0[8], xf1[8];
        #pragma unroll
        for (int j = 0; j < 8; j++) {
            xf0[j] = bp[rb0 + j * HWS];
            xf1[j] = bp[rb1 + j * HWS];
        }
        f32x4 sv[4];
        {
            const f32x4* ssv = (const f32x4*)&ss[gl * BK + q * 8];
            #pragma unroll
            for (int k = 0; k < 4; k++) sv[k] = ssv[k];
        }
        bf16x8 b0, b1;
        #pragma unroll
        for (int j = 0; j < 8; j++) {
            const float sc = sv[j >> 1][(j & 1) * 2];
            const float sh = sv[j >> 1][(j & 1) * 2 + 1];
            b0[j] = (bf16)fmaxf(fmaf(xf0[j], sc, sh), 0.f);
            b1[j] = (bf16)fmaxf(fmaf(xf1[j], sc, sh), 0.f);
        }
        #pragma unroll
        for (int mt = 0; mt < 3; mt++) {
            acc[mt][0] = __builtin_amdgcn_mfma_f32_16x16x32_bf16(ar[mt], b0, acc[mt][0], 0, 0, 0);
            acc[mt][1] = __builtin_amdgcn_mfma_f32_16x16x32_bf16(ar[mt], b1, acc[mt][1], 0, 0, 0);
        }
        int tk = gl + 2; if (tk > HALF - 1) tk = HALF - 1;
        #pragma unroll
        for (int mt = 0; mt < 3; mt++)
            ar[mt] = *(const bf16x8*)(apL + (size_t)(g0 + tk) * 6144 + (size_t)(mt * 512));
        __builtin_amdgcn_sched_barrier(0);
    };

    // 15 counted parity pairs (gl=0..29), then 3 drain-tail steps.
    #pragma unroll 1
    for (int it = 0; it < 15; ++it) {
        STEP(2 * it,     arE, true);
        STEP(2 * it + 1, arO, true);
    }
    STEP(30, arE, false);
    STEP(31, arO, false);
    STEP(32, arE, false);

    // epilogue: partial sums -> par[kh][b][row][hw] (R16-proven, disjoint).
    float* ob = par + ((size_t)kh * 256 + b) * OUTEL;
    const int hw1 = ng * 32 + 16 + l15;
    #pragma unroll
    for (int mt = 0; mt < 3; mt++) {
        const int row0 = mg * 48 + mt * 16 + q * 4;
        #pragma unroll
        for (int r = 0; r < 4; r++)
            ob[(size_t)(row0 + r) * HWS + hwc0] = acc[mt][0][r];
        if (hw1 < HWS) {
            #pragma unroll
            for (int r = 0; r < 4; r++)
                ob[(size_t)(row0 + r) * HWS + hw1] = acc[mt][1][r];
        }
    }
}

// ---------- kernel 3: sum the two K-half partials (R16-proven) ----------
__global__ __launch_bounds__(256)
void add_kernel(const float* __restrict__ par, float* __restrict__ out) {
    const size_t i = (size_t)blockIdx.x * 256 + threadIdx.x;   // f32x4 index
    const size_t n4 = (size_t)256 * OUTEL / 4;                 // 602112
    if (i >= n4) return;
    const f32x4 a = *(const f32x4*)(par + i * 4);
    const f32x4 c = *(const f32x4*)(par + (size_t)256 * OUTEL + i * 4);
    f32x4 o;
    #pragma unroll
    for (int j = 0; j < 4; j++) o[j] = a[j] + c[j];
    *(f32x4*)(out + i * 4) = o;
}

extern "C" void kernel_launch(void* const* d_in, const int* in_sizes, int n_in,
                              void* d_out, int out_size, void* d_ws, size_t ws_size,
                              hipStream_t stream) {
    const float* x     = (const float*)d_in[0];
    const float* gamma = (const float*)d_in[1];
    const float* beta  = (const float*)d_in[2];
    const float* rmean = (const float*)d_in[3];
    const float* rvar  = (const float*)d_in[4];
    const float* W     = (const float*)d_in[5];
    float* out = (float*)d_out;

    bf16*  Wb  = (bf16*)d_ws;                              // 811,008 B
    float* par = (float*)((char*)d_ws + (1 << 20));        // 2 x 9.63 MB partials

    w_repack_kernel<<<dim3(198), dim3(256), 0, stream>>>(W, Wb);
    fused_kernel<<<dim3(512), dim3(512), 0, stream>>>(
        x, gamma, beta, rmean, rvar, Wb, par);
    add_kernel<<<dim3((256 * OUTEL / 4 + 255) / 256), dim3(256), 0, stream>>>(par, out);
}

// Round 11
// 181.697 us; speedup vs baseline: 1.0169x; 1.0169x over previous
//
#include <hip/hip_runtime.h>
#include <hip/hip_bf16.h>

// out[b,o,hw] = sum_c W[o,c] * relu(x[b,c,hw]*scale[c] + shift[c])
// B=256, Cin=2112, Cout=192, HW=49, fp32 in HBM, bf16 MFMA internally.
//
// R18: LONG MFMA CLUSTERS. Seven structures all sat at fused ~50us with
// MfmaUtil ~7%; the invariant was 6 MFMA (~96cy) per barrier-phase vs a
// ~1300cy fixed phase cost (m233's 2-phase stall, unmoved by barrier
// count / vmcnt edits). Fix per m201/m218: make each barrier guard a
// LONG register-only MFMA cluster with operands ds_read BEFORE the
// barrier. 4-wave blocks: wave = 3 M-tiles x ALL 4 N-tiles (acc 48
// VGPR); phase = 2 granules: [8x ds_read_b128 | stage 2 slabs (R8's
// proven scatter+swizzle) | x-prefetch (2-phase distance) | lgkmcnt(0)
// | barrier | 24 MFMA | A-reload]. One barrier per 64 channels; 4-slot
// LDS ring, pair-parity unrolled so all slot offsets are compile-time.
// K-split x2 + par/add epilogue verbatim from R16 (passed).

#define CIN    2112
#define COUT   192
#define HWS    49
#define BK     32
#define NK32   (CIN / BK)          // 66 granules total
#define HALF   (NK32 / 2)          // 33 granules per K-half
#define CHALF  (HALF * BK)         // 1056 channels per half
#define EPSV   1e-5f
#define SLAB   (BK * HWS)          // 1568 elems per granule slab
#define OUTEL  (COUT * HWS)        // 9408 floats per image

typedef __bf16 bf16;
typedef __attribute__((ext_vector_type(8))) __bf16 bf16x8;
typedef __attribute__((ext_vector_type(4))) float  f32x4;

// ---------- kernel 1: W fp32 -> bf16 in A-fragment order (unchanged) ----------
__global__ __launch_bounds__(256)
void w_repack_kernel(const float* __restrict__ W, bf16* __restrict__ Wb) {
    const int t = blockIdx.x * 256 + threadIdx.x;       // 66*12*64 = 50688
    if (t >= NK32 * 12 * 64) return;
    const int lane = t & 63;
    const int gmt  = (t >> 6) % 12;
    const int ks   = t / (12 * 64);
    const int row  = gmt * 16 + (lane & 15);
    const int k    = ks * BK + (lane >> 4) * 8;
    const float* src = W + (size_t)row * CIN + k;
    f32x4 a = *(const f32x4*)src;
    f32x4 c = *(const f32x4*)(src + 4);
    bf16x8 o;
    #pragma unroll
    for (int j = 0; j < 4; j++) { o[j] = (bf16)a[j]; o[j + 4] = (bf16)c[j]; }
    *(bf16x8*)(Wb + (size_t)t * 8) = o;
}

// ---------- kernel 2: fused BN+ReLU+pack+GEMM, 24-MFMA phases ----------
__global__ __launch_bounds__(256, 2)
void fused_kernel(const float* __restrict__ x,
                  const float* __restrict__ gamma,
                  const float* __restrict__ beta,
                  const float* __restrict__ rmean,
                  const float* __restrict__ rvar,
                  const bf16* __restrict__ Wb,
                  float* __restrict__ par)
{
    __shared__ float2 ss[CHALF + 2];                 // half's BN params (+pad)
    __shared__ __align__(16) bf16 bt[4][SLAB];       // 4-slot granule ring

    const int tid = threadIdx.x;
    const int b   = blockIdx.x >> 1;                 // image
    const int kh  = blockIdx.x & 1;                  // K-half
    const int g0  = kh * HALF;                       // first global granule
    const int c0  = kh * CHALF;                      // first channel

    // BN params for this half -> LDS
    for (int c = tid; c < CHALF; c += 256) {
        const int gc = c0 + c;
        float inv = rsqrtf(rvar[gc] + EPSV);
        float s   = gamma[gc] * inv;
        ss[c] = make_float2(s, beta[gc] - rmean[gc] * s);
    }
    if (tid < 2) ss[CHALF + tid] = make_float2(0.f, 0.f);

    // ---- staging role: threads 0..195 own 8 consecutive floats of a slab
    const bool act = tid < (SLAB / 8);               // 196
    const int fb  = tid * 8;
    const int cl0 = fb / HWS;
    const int hw0 = fb - cl0 * HWS;
    const int jw  = (hw0 + 8 <= HWS) ? 8 : (HWS - hw0);
    int addrs[8];
    #pragma unroll
    for (int j = 0; j < 8; j++) {
        int hw = hw0 + j, cl = cl0;
        if (hw >= HWS) { hw -= HWS; cl += 1; }
        const int rot = ((cl >> 3) + (hw >> 2)) & 3;      // bank swizzle
        addrs[j] = hw * BK + rot * 8 + (cl & 7);
    }
    const float* xs = x + (size_t)b * (CIN * HWS) + (size_t)c0 * HWS + fb;

    // ---- compute role: 4 waves; wave = 3 M-tiles x 4 N-tiles (full width)
    const int lane = tid & 63;
    const int wv   = tid >> 6;        // 0..3 : rows wv*48..
    const int l15  = lane & 15;
    const int q    = lane >> 4;

    int bad[4];                       // B-frag LDS addrs per N-tile
    #pragma unroll
    for (int nt = 0; nt < 4; nt++) {
        int hwct = nt * 16 + l15;
        if (hwct > 48) hwct = 48;     // nt=3 lanes 1..15 dup col 48
        bad[nt] = hwct * BK + ((q + (hwct >> 2)) & 3) * 8;
    }

    const bf16* apL = Wb + (size_t)(wv * 3) * 512 + (size_t)lane * 8;

    f32x4 acc[3][4];
    #pragma unroll
    for (int mt = 0; mt < 3; mt++)
        #pragma unroll
        for (int nt = 0; nt < 4; nt++) acc[mt][nt] = (f32x4)(0.f);

    // helpers ------------------------------------------------------------
    auto STAGE = [&](int s, const f32x4& v0, const f32x4& v1, bf16* dst) {
        // BN+ReLU+pack slab s (local granule) into ring slot dst
        const int cb = s * BK;
        const float2 s0 = ss[cb + cl0];
        const float2 s1 = ss[cb + cl0 + 1];
        #pragma unroll
        for (int j = 0; j < 8; j++) {
            const float xj = (j < 4) ? v0[j] : v1[j - 4];
            const float sc = (j >= jw) ? s1.x : s0.x;
            const float sh = (j >= jw) ? s1.y : s0.y;
            dst[addrs[j]] = (bf16)fmaxf(fmaf(xj, sc, sh), 0.f);
        }
    };
    auto XLOAD = [&](int s, f32x4& v0, f32x4& v1) {
        int ln = s; if (ln > HALF - 1) ln = HALF - 1;       // clamp (discard)
        v0 = *(const f32x4*)(xs + (size_t)ln * SLAB);
        v1 = *(const f32x4*)(xs + (size_t)ln * SLAB + 4);
    };

    // prologue: stage slabs 0,1; xv sets A (slabs 2,3) and B (slabs 4,5);
    // A-frags for granules 0,1.
    f32x4 tA0, tA1, tB0, tB1;
    f32x4 xA00, xA01, xA10, xA11;     // set A: two granules (even phases)
    f32x4 xB00, xB01, xB10, xB11;     // set B: two granules (odd phases)
    bf16x8 arE[3], arO[3];
    #pragma unroll
    for (int mt = 0; mt < 3; mt++) {
        arE[mt] = *(const bf16x8*)(apL + (size_t)(g0 + 0) * 6144 + (size_t)(mt * 512));
        arO[mt] = *(const bf16x8*)(apL + (size_t)(g0 + 1) * 6144 + (size_t)(mt * 512));
    }
    if (act) {
        XLOAD(0, tA0, tA1);  XLOAD(1, tB0, tB1);
        XLOAD(2, xA00, xA01); XLOAD(3, xA10, xA11);
        XLOAD(4, xB00, xB01); XLOAD(5, xB10, xB11);
    }
    __syncthreads();                   // ss ready
    if (act) { STAGE(0, tA0, tA1, &bt[0][0]); STAGE(1, tB0, tB1, &bt[1][0]); }
    asm volatile("s_waitcnt lgkmcnt(0)" ::: "memory");
    __builtin_amdgcn_s_barrier();
    __builtin_amdgcn_sched_barrier(0);

    // one phase: granules ga=2p, gb=2p+1 in ring slots ra,rb; stage into
    // wa,wb; refill this parity's xv set for phase p+2 (2-phase distance).
    auto PHASE = [&](int p, int ra, int rb, int wa, int wb,
                     f32x4& v00, f32x4& v01, f32x4& v10, f32x4& v11) {
        bf16x8 bfA[4], bfB[4];
        #pragma unroll
        for (int nt = 0; nt < 4; nt++) {
            bfA[nt] = *(const bf16x8*)&bt[ra][bad[nt]];
            bfB[nt] = *(const bf16x8*)&bt[rb][bad[nt]];
        }
        if (act) {
            const int sa = 2 * p + 2, sb = 2 * p + 3;
            if (sa <= HALF - 1) STAGE(sa, v00, v01, &bt[wa][0]);
            if (sb <= HALF - 1) STAGE(sb, v10, v11, &bt[wb][0]);
            XLOAD(2 * p + 6, v00, v01);
            XLOAD(2 * p + 7, v10, v11);
        }
        asm volatile("s_waitcnt lgkmcnt(0)" ::: "memory");
        __builtin_amdgcn_s_barrier();
        __builtin_amdgcn_sched_barrier(0);
        #pragma unroll
        for (int mt = 0; mt < 3; mt++)
            #pragma unroll
            for (int nt = 0; nt < 4; nt++)
                acc[mt][nt] = __builtin_amdgcn_mfma_f32_16x16x32_bf16(arE[mt], bfA[nt], acc[mt][nt], 0, 0, 0);
        #pragma unroll
        for (int mt = 0; mt < 3; mt++)
            #pragma unroll
            for (int nt = 0; nt < 4; nt++)
                acc[mt][nt] = __builtin_amdgcn_mfma_f32_16x16x32_bf16(arO[mt], bfB[nt], acc[mt][nt], 0, 0, 0);
        int ta = 2 * p + 2; if (ta > HALF - 1) ta = HALF - 1;
        int tb = 2 * p + 3; if (tb > HALF - 1) tb = HALF - 1;
        #pragma unroll
        for (int mt = 0; mt < 3; mt++) {
            arE[mt] = *(const bf16x8*)(apL + (size_t)(g0 + ta) * 6144 + (size_t)(mt * 512));
            arO[mt] = *(const bf16x8*)(apL + (size_t)(g0 + tb) * 6144 + (size_t)(mt * 512));
        }
        __builtin_amdgcn_sched_barrier(0);
    };

    // 16 phases = granules 0..31 (pair-parity keeps ring slots static)
    #pragma unroll 1
    for (int it = 0; it < 8; ++it) {
        PHASE(2 * it,     0, 1, 2, 3, xA00, xA01, xA10, xA11);
        PHASE(2 * it + 1, 2, 3, 0, 1, xB00, xB01, xB10, xB11);
    }

    // tail: granule 32 (slot 0), A-frags already in arE (loaded at p=15)
    {
        bf16x8 bfT[4];
        #pragma unroll
        for (int nt = 0; nt < 4; nt++)
            bfT[nt] = *(const bf16x8*)&bt[0][bad[nt]];
        asm volatile("s_waitcnt lgkmcnt(0)" ::: "memory");
        __builtin_amdgcn_sched_barrier(0);
        #pragma unroll
        for (int mt = 0; mt < 3; mt++)
            #pragma unroll
            for (int nt = 0; nt < 4; nt++)
                acc[mt][nt] = __builtin_amdgcn_mfma_f32_16x16x32_bf16(arE[mt], bfT[nt], acc[mt][nt], 0, 0, 0);
    }

    // epilogue: partials -> par[kh][b][row][hw]. col=l15 -> hw, row=q*4+r.
    float* ob = par + ((size_t)kh * 256 + b) * OUTEL;
    #pragma unroll
    for (int mt = 0; mt < 3; mt++) {
        const int row0 = wv * 48 + mt * 16 + q * 4;
        #pragma unroll
        for (int nt = 0; nt < 4; nt++) {
            const int hw = nt * 16 + l15;
            if (hw < HWS) {
                #pragma unroll
                for (int r = 0; r < 4; r++)
                    ob[(size_t)(row0 + r) * HWS + hw] = acc[mt][nt][r];
            }
        }
    }
}

// ---------- kernel 3: sum the two K-half partials (R16-proven) ----------
__global__ __launch_bounds__(256)
void add_kernel(const float* __restrict__ par, float* __restrict__ out) {
    const size_t i = (size_t)blockIdx.x * 256 + threadIdx.x;   // f32x4 index
    const size_t n4 = (size_t)256 * OUTEL / 4;                 // 602112
    if (i >= n4) return;
    const f32x4 a = *(const f32x4*)(par + i * 4);
    const f32x4 c = *(const f32x4*)(par + (size_t)256 * OUTEL + i * 4);
    f32x4 o;
    #pragma unroll
    for (int j = 0; j < 4; j++) o[j] = a[j] + c[j];
    *(f32x4*)(out + i * 4) = o;
}

extern "C" void kernel_launch(void* const* d_in, const int* in_sizes, int n_in,
                              void* d_out, int out_size, void* d_ws, size_t ws_size,
                              hipStream_t stream) {
    const float* x     = (const float*)d_in[0];
    const float* gamma = (const float*)d_in[1];
    const float* beta  = (const float*)d_in[2];
    const float* rmean = (const float*)d_in[3];
    const float* rvar  = (const float*)d_in[4];
    const float* W     = (const float*)d_in[5];
    float* out = (float*)d_out;

    bf16*  Wb  = (bf16*)d_ws;                              // 811,008 B
    float* par = (float*)((char*)d_ws + (1 << 20));        // 2 x 9.63 MB partials

    w_repack_kernel<<<dim3(198), dim3(256), 0, stream>>>(W, Wb);
    fused_kernel<<<dim3(512), dim3(256), 0, stream>>>(
        x, gamma, beta, rmean, rvar, Wb, par);
    add_kernel<<<dim3((256 * OUTEL / 4 + 255) / 256), dim3(256), 0, stream>>>(par, out);
}